// Round 13
// baseline (914.584 us; speedup 1.0000x reference)
//
#include <hip/hip_runtime.h>
#include <cstdint>

typedef __bf16 bf16x8 __attribute__((ext_vector_type(8)));
typedef __bf16 bf16x4 __attribute__((ext_vector_type(4)));
typedef __bf16 bf16x2 __attribute__((ext_vector_type(2)));
typedef float  f32x4  __attribute__((ext_vector_type(4)));

static constexpr int Hn = 16, Sn = 2048, Dn = 128;
static constexpr float SCALE_INV = 0.088388347648318447f; // 1/sqrt(128)
static constexpr float M0 = 4.0f;  // static softmax shift (max s ~6.2 for N(0,1) scores)

// ws layout (float units):
//   [0)            mask  u32[4,194,304]  (2^27 dropout bits, 1=keep)   16.8 MB
//   [4,194,304)    Kb    bf16[8,388,608]                               16.8 MB
//   [8,388,608)    Vt    bf16[8,388,608] transposed [bh][d][kv]        16.8 MB
//   [12,582,912)   U     f32[2][32][2048][128] split partials          67.1 MB
//   [29,360,128)   LP    f32[2][65,536]  l partials                     0.5 MB
static constexpr size_t WS_KB_F  = 4194304;
static constexpr size_t WS_VT_F  = 8388608;
static constexpr size_t WS_U_F   = 12582912;
static constexpr size_t WS_LP_F  = 29360128;
static constexpr size_t WS_U_HALF = 8388608;   // floats per U half
static constexpr size_t NEED_B = 12582912ull * 4ull;              // 50.3 MB: mask+Kb+Vt
static constexpr size_t NEED_A = (29360128ull + 131072ull) * 4ull; // 118 MB: + U + LP

__device__ __forceinline__ uint32_t rotl32(uint32_t v, int s) {
  return (v << s) | (v >> (32 - s));
}

// JAX threefry2x32 (partitionable), key(42): k0=0, k1=42, k2=0x1BD11BF0
__device__ __forceinline__ void tf2x32(uint32_t c0, uint32_t c1,
                                       uint32_t& o0, uint32_t& o1) {
  const uint32_t K1 = 42u, K2 = 0x1BD11BF0u;
  uint32_t x0 = c0, x1 = c1 + K1;
#define TF_R4(a,b,c,d) \
  x0 += x1; x1 = rotl32(x1,a) ^ x0; \
  x0 += x1; x1 = rotl32(x1,b) ^ x0; \
  x0 += x1; x1 = rotl32(x1,c) ^ x0; \
  x0 += x1; x1 = rotl32(x1,d) ^ x0;
  TF_R4(13,15,26,6)   x0 += K1;            x1 += K2 + 1u;
  TF_R4(17,29,16,24)  x0 += K2;            x1 += 2u;
  TF_R4(13,15,26,6)   /* +K0 */            x1 += K1 + 3u;
  TF_R4(17,29,16,24)  x0 += K1;            x1 += K2 + 4u;
  TF_R4(13,15,26,6)   x0 += K2;            x1 += 5u;
#undef TF_R4
  o0 = x0; o1 = x1;
}

__device__ __forceinline__ bf16x8 cvt8(f32x4 a, f32x4 b) {
  bf16x8 r;
  r[0] = (__bf16)a[0]; r[1] = (__bf16)a[1]; r[2] = (__bf16)a[2]; r[3] = (__bf16)a[3];
  r[4] = (__bf16)b[0]; r[5] = (__bf16)b[1]; r[6] = (__bf16)b[2]; r[7] = (__bf16)b[3];
  return r;
}

// --- prep: K->bf16, V->bf16 transposed, dropout mask bit-gen (merged so the
//     memory-bound cast blocks overlap the VALU-bound threefry blocks) ---
__global__ __launch_bounds__(256) void prep_all(
    const float* __restrict__ K, const float* __restrict__ V,
    __bf16* __restrict__ Kb, __bf16* __restrict__ Vt,
    uint32_t* __restrict__ mask)
{
  int bid = (int)blockIdx.x;
  if (bid < 4096) {              // K cast: 4096*256*8 = 8,388,608 elems
    size_t base = ((size_t)bid * 256 + threadIdx.x) * 8;
    f32x4 a = *(const f32x4*)(K + base);
    f32x4 b = *(const f32x4*)(K + base + 4);
    *(bf16x8*)(Kb + base) = cvt8(a, b);
  } else if (bid < 12288) {      // V transpose-cast: 8192 blocks of 32x32 tiles
    bid -= 4096;
    int bh = bid >> 8, kvt = (bid >> 2) & 63, dt = bid & 3;
    __shared__ float tile[32][33];
    int r = (int)threadIdx.x >> 3, c4 = ((int)threadIdx.x & 7) * 4;
    const float* Vb = V + ((size_t)bh * Sn + (size_t)kvt * 32 + r) * Dn + dt * 32 + c4;
    f32x4 v = *(const f32x4*)Vb;
    tile[r][c4] = v[0]; tile[r][c4 + 1] = v[1];
    tile[r][c4 + 2] = v[2]; tile[r][c4 + 3] = v[3];
    __syncthreads();
    bf16x4 o;
    o[0] = (__bf16)tile[c4][r];     o[1] = (__bf16)tile[c4 + 1][r];
    o[2] = (__bf16)tile[c4 + 2][r]; o[3] = (__bf16)tile[c4 + 3][r];
    __bf16* dst = Vt + ((size_t)bh * Dn + dt * 32 + r) * Sn + (size_t)kvt * 32 + c4;
    *(bf16x4*)dst = o;
  } else {                       // mask: 16384 blocks, 1 u32 word (32 bits) / thread
    uint32_t widx = (uint32_t)(bid - 12288) * 256u + (uint32_t)threadIdx.x;
    uint32_t base = widx << 5;
    uint32_t w = 0;
    #pragma unroll 8
    for (int j = 0; j < 32; ++j) {
      uint32_t y0, y1;
      tf2x32(0u, base + (uint32_t)j, y0, y1);
      uint32_t keep = (((y0 ^ y1) >> 31) ^ 1u);   // 1 = keep (MSB clear)
      w |= keep << j;
    }
    mask[widx] = w;
  }
}

// --- main attention: no LDS/barriers; bf16 K,V + precomputed mask from ws ---
__global__ __launch_bounds__(256, 4) void attn_bf16(
    const float* __restrict__ Qg, const __bf16* __restrict__ Kb,
    const __bf16* __restrict__ Vt, const uint32_t* __restrict__ mask,
    float* __restrict__ Og, float* __restrict__ U, float* __restrict__ LP,
    int split)
{
  const int tid  = threadIdx.x;
  const int lane = tid & 63;
  const int wv   = tid >> 6;
  const int g    = lane >> 4;
  const int qp   = lane & 15;

  const int bidl = (int)(blockIdx.x & 1023);
  const int half = (int)(blockIdx.x >> 10);   // 0 when grid=1024
  const int qt  = bidl & 31;
  const int bh  = bidl >> 5;
  const uint32_t b_hi = (uint32_t)(bh >> 4) << 26;
  const uint32_t h_hi = (uint32_t)(bh & 15) << 22;

  const int kvlo = split ? half * 1024 : 0;
  const int kvhi = kvlo + (split ? 1024 : 2048);

  const int q0 = qt * 64 + wv * 16;

  const size_t bhOff = (size_t)bh * Sn * Dn;
  const float*  Qb  = Qg + bhOff;
  const __bf16* Kbh = Kb + bhOff;
  const __bf16* Vbh = Vt + bhOff;   // [d][kv]
  float*        Ob  = Og + bhOff;

  // Q fragments (B operand), pre-scaled. q row = qp, d = 32c + 8g + j
  bf16x8 qf[4];
  {
    const float* qrow = Qb + (size_t)(q0 + qp) * Dn + g * 8;
    #pragma unroll
    for (int c = 0; c < 4; ++c) {
      f32x4 a = *(const f32x4*)(qrow + c * 32);
      f32x4 b = *(const f32x4*)(qrow + c * 32 + 4);
      #pragma unroll
      for (int j = 0; j < 4; ++j) { a[j] *= SCALE_INV; b[j] *= SCALE_INV; }
      qf[c] = cvt8(a, b);
    }
  }

  f32x4 oacc[8];
  #pragma unroll
  for (int n = 0; n < 8; ++n) { f32x4 z = {0.f,0.f,0.f,0.f}; oacc[n] = z; }
  float l_run = 0.f;

  const uint32_t idx_base = b_hi + h_hi + ((uint32_t)(q0 + qp) << 11);
  const uint32_t* mrow = mask + (idx_base >> 5);   // 64 words per q-row

  for (int kv0 = kvlo; kv0 < kvhi; kv0 += 32) {
    // ---- S^T = K . Q^T, two 16-kv tiles ----
    f32x4 st0 = {0.f,0.f,0.f,0.f}, st1 = {0.f,0.f,0.f,0.f};
    {
      const __bf16* kr0 = Kbh + (size_t)(kv0 + qp) * Dn + g * 8;
      const __bf16* kr1 = kr0 + (size_t)16 * Dn;
      #pragma unroll
      for (int c = 0; c < 4; ++c) {
        bf16x8 ka = *(const bf16x8*)(kr0 + c * 32);
        st0 = __builtin_amdgcn_mfma_f32_16x16x32_bf16(ka, qf[c], st0, 0, 0, 0);
        bf16x8 kb2 = *(const bf16x8*)(kr1 + c * 32);
        st1 = __builtin_amdgcn_mfma_f32_16x16x32_bf16(kb2, qf[c], st1, 0, 0, 0);
      }
    }

    // ---- softmax (static shift) + mask-bit dropout + bf16x2 pack ----
    // lane holds q = qp, kv = kv0 + 16T + 4g + r
    const uint32_t mw = mrow[kv0 >> 5];   // all 8 bits this lane needs
    float s[8] = { st0[0], st0[1], st0[2], st0[3], st1[0], st1[1], st1[2], st1[3] };
    uint32_t pk[4];
    float l_add = 0.f;
    #pragma unroll
    for (int m = 0; m < 4; ++m) {
      float p0 = __expf(s[2*m]     - M0);
      float p1 = __expf(s[2*m + 1] - M0);
      l_add += p0 + p1;
      const int b0 = (m >> 1) * 16 + g * 4 + ((2*m) & 3);
      if (!((mw >> b0) & 1u))       p0 = 0.f;
      if (!((mw >> (b0 + 1)) & 1u)) p1 = 0.f;
      bf16x2 pr; pr[0] = (__bf16)p0; pr[1] = (__bf16)p1;
      union { bf16x2 h; uint32_t u; } cv; cv.h = pr;
      pk[m] = cv.u;
    }
    l_run += l_add;

    // ---- P: C-layout -> A-layout (select AFTER shuffle: src-lane semantics) ----
    union { uint32_t u[4]; bf16x8 v; } pu;
    #pragma unroll
    for (int w = 0; w < 4; ++w) {
      int srcl = ((2 * (g & 1) + (w >> 1)) << 4) | qp;
      uint32_t lo = (uint32_t)__shfl((int)pk[w & 1],       srcl);  // tile T=0
      uint32_t hi = (uint32_t)__shfl((int)pk[2 + (w & 1)], srcl);  // tile T=1
      pu.u[w] = (g >= 2) ? hi : lo;
    }
    bf16x8 pa = pu.v;

    // ---- PV: B-frags straight from transposed global V ----
    const __bf16* vcol = Vbh + (size_t)kv0 + (size_t)(g * 8);
    #pragma unroll
    for (int n = 0; n < 8; ++n) {
      bf16x8 vb = *(const bf16x8*)(vcol + (size_t)(n * 16 + qp) * Sn);
      oacc[n] = __builtin_amdgcn_mfma_f32_16x16x32_bf16(pa, vb, oacc[n], 0, 0, 0);
    }
  }

  // l(qp): sum across g-groups (all lanes get full row sum)
  l_run += __shfl_xor(l_run, 16);
  l_run += __shfl_xor(l_run, 32);

  if (!split) {
    float f = 2.0f / l_run;
    float fr[4];
    #pragma unroll
    for (int r = 0; r < 4; ++r) fr[r] = __shfl(f, g * 4 + r);
    float* orow = Ob + (size_t)q0 * Dn;
    #pragma unroll
    for (int n = 0; n < 8; ++n) {
      #pragma unroll
      for (int r = 0; r < 4; ++r) {
        orow[(size_t)(g * 4 + r) * Dn + n * 16 + qp] = oacc[n][r] * fr[r];
      }
    }
  } else {
    // static shift => partials are ADDITIVE: write unnormalized U + l
    float* Urow = U + (size_t)half * WS_U_HALF + bhOff + (size_t)q0 * Dn;
    #pragma unroll
    for (int n = 0; n < 8; ++n) {
      #pragma unroll
      for (int r = 0; r < 4; ++r) {
        Urow[(size_t)(g * 4 + r) * Dn + n * 16 + qp] = oacc[n][r];
      }
    }
    if (lane < 16) {
      LP[(size_t)half * 65536 + (size_t)bh * Sn + (size_t)(q0 + qp)] = l_run;
    }
  }
}

__global__ __launch_bounds__(256) void attn_combine(
    const float* __restrict__ U, const float* __restrict__ LP,
    float* __restrict__ Og)
{
  int idx = (int)blockIdx.x * 256 + (int)threadIdx.x;
  size_t row = (size_t)(idx >> 5);
  int c4 = (idx & 31) * 4;
  float inv = 2.0f / (LP[row] + LP[65536 + row]);
  const f32x4 u1 = *(const f32x4*)(U + row * Dn + c4);
  const f32x4 u2 = *(const f32x4*)(U + WS_U_HALF + row * Dn + c4);
  f32x4 o;
  #pragma unroll
  for (int j = 0; j < 4; ++j) o[j] = (u1[j] + u2[j]) * inv;
  *(f32x4*)(Og + row * Dn + c4) = o;
}

// --- legacy fallback (round-5 verified, fp32 inputs, no ws) ---
__global__ __launch_bounds__(256, 4) void attn_fwd_legacy(
    const float* __restrict__ Qg, const float* __restrict__ Kg,
    const float* __restrict__ Vg, float* __restrict__ Og)
{
  const int tid  = threadIdx.x;
  const int lane = tid & 63;
  const int wv   = tid >> 6;
  const int g    = lane >> 4;
  const int qp   = lane & 15;

  const int bid = (int)blockIdx.x;
  const int qt  = bid & 31;
  const int bh  = bid >> 5;
  const uint32_t b_hi = (uint32_t)(bh >> 4) << 26;
  const uint32_t h_hi = (uint32_t)(bh & 15) << 22;

  const int q0 = qt * 64 + wv * 16;
  __shared__ __bf16 Vts[128 * 40];

  const size_t bhOff = (size_t)bh * Sn * Dn;
  const float* Qb = Qg + bhOff;
  const float* Kb = Kg + bhOff;
  const float* Vb = Vg + bhOff;
  float*       Ob = Og + bhOff;

  bf16x8 qf[4];
  {
    const float* qrow = Qb + (size_t)(q0 + qp) * Dn + g * 8;
    #pragma unroll
    for (int c = 0; c < 4; ++c) {
      f32x4 a = *(const f32x4*)(qrow + c * 32);
      f32x4 b = *(const f32x4*)(qrow + c * 32 + 4);
      #pragma unroll
      for (int j = 0; j < 4; ++j) { a[j] *= SCALE_INV; b[j] *= SCALE_INV; }
      qf[c] = cvt8(a, b);
    }
  }

  f32x4 oacc[8];
  #pragma unroll
  for (int n = 0; n < 8; ++n) { f32x4 z = {0.f,0.f,0.f,0.f}; oacc[n] = z; }
  float m_run = -1e30f, l_run = 0.f;
  const int vr = (tid & 15) * 2;
  const int vc = (tid >> 4) * 8;
  const uint32_t idx_base = b_hi + h_hi + ((uint32_t)(q0 + qp) << 11);

  for (int kv0 = 0; kv0 < Sn; kv0 += 32) {
    const float* vp = Vb + (size_t)(kv0 + vr) * Dn + vc;
    f32x4 v0a = *(const f32x4*)(vp);
    f32x4 v0b = *(const f32x4*)(vp + 4);
    f32x4 v1a = *(const f32x4*)(vp + Dn);
    f32x4 v1b = *(const f32x4*)(vp + Dn + 4);

    f32x4 st0 = {0.f,0.f,0.f,0.f}, st1 = {0.f,0.f,0.f,0.f};
    {
      const float* krow0 = Kb + (size_t)(kv0 + qp) * Dn + g * 8;
      const float* krow1 = krow0 + (size_t)16 * Dn;
      #pragma unroll
      for (int c = 0; c < 4; ++c) {
        f32x4 a0 = *(const f32x4*)(krow0 + c * 32);
        f32x4 b0 = *(const f32x4*)(krow0 + c * 32 + 4);
        st0 = __builtin_amdgcn_mfma_f32_16x16x32_bf16(cvt8(a0, b0), qf[c], st0, 0, 0, 0);
        f32x4 a1 = *(const f32x4*)(krow1 + c * 32);
        f32x4 b1 = *(const f32x4*)(krow1 + c * 32 + 4);
        st1 = __builtin_amdgcn_mfma_f32_16x16x32_bf16(cvt8(a1, b1), qf[c], st1, 0, 0, 0);
      }
    }

    __syncthreads();
    #pragma unroll
    for (int i = 0; i < 8; ++i) {
      float x0 = (i < 4) ? v0a[i] : v0b[i - 4];
      float x1 = (i < 4) ? v1a[i] : v1b[i - 4];
      bf16x2 pr; pr[0] = (__bf16)x0; pr[1] = (__bf16)x1;
      *(bf16x2*)&Vts[(vc + i) * 40 + vr] = pr;
    }
    __syncthreads();

    float s[8] = { st0[0], st0[1], st0[2], st0[3], st1[0], st1[1], st1[2], st1[3] };
    float tmax = s[0];
    #pragma unroll
    for (int i = 1; i < 8; ++i) tmax = fmaxf(tmax, s[i]);
    tmax = fmaxf(tmax, __shfl_xor(tmax, 16));
    tmax = fmaxf(tmax, __shfl_xor(tmax, 32));
    float m_new = fmaxf(m_run, tmax);
    float alpha = __expf(m_run - m_new);

    float p[8], pd[8], psum = 0.f;
    #pragma unroll
    for (int i = 0; i < 8; ++i) {
      p[i] = __expf(s[i] - m_new);
      psum += p[i];
      uint32_t idx = idx_base + (uint32_t)(kv0 + (i >> 2) * 16 + g * 4 + (i & 3));
      uint32_t y0, y1;
      tf2x32(0u, idx, y0, y1);
      pd[i] = ((int)(y0 ^ y1) < 0) ? 0.f : p[i];
    }
    psum += __shfl_xor(psum, 16);
    psum += __shfl_xor(psum, 32);
    l_run = l_run * alpha + psum;
    m_run = m_new;

    float alr[4];
    #pragma unroll
    for (int r = 0; r < 4; ++r) alr[r] = __shfl(alpha, g * 4 + r);
    #pragma unroll
    for (int n = 0; n < 8; ++n) {
      f32x4 t = oacc[n];
      t[0] *= alr[0]; t[1] *= alr[1]; t[2] *= alr[2]; t[3] *= alr[3];
      oacc[n] = t;
    }

    bf16x8 pa;
    #pragma unroll
    for (int j = 0; j < 8; ++j) {
      int src = ((2 * (g & 1) + (j >> 2)) << 4) | qp;
      float v0 = __shfl(pd[j & 3],       src);
      float v1 = __shfl(pd[4 + (j & 3)], src);
      pa[j] = (__bf16)((g >= 2) ? v1 : v0);
    }

    #pragma unroll
    for (int n = 0; n < 8; ++n) {
      bf16x8 vb = *(const bf16x8*)&Vts[(n * 16 + qp) * 40 + g * 8];
      oacc[n] = __builtin_amdgcn_mfma_f32_16x16x32_bf16(pa, vb, oacc[n], 0, 0, 0);
    }
  }

  float f = 2.0f / l_run;
  float fr[4];
  #pragma unroll
  for (int r = 0; r < 4; ++r) fr[r] = __shfl(f, g * 4 + r);
  float* orow = Ob + (size_t)q0 * Dn;
  #pragma unroll
  for (int n = 0; n < 8; ++n) {
    #pragma unroll
    for (int r = 0; r < 4; ++r) {
      orow[(size_t)(g * 4 + r) * Dn + n * 16 + qp] = oacc[n][r] * fr[r];
    }
  }
}

extern "C" void kernel_launch(void* const* d_in, const int* in_sizes, int n_in,
                              void* d_out, int out_size, void* d_ws, size_t ws_size,
                              hipStream_t stream) {
  (void)in_sizes; (void)n_in; (void)out_size;
  const float* Q = (const float*)d_in[0];
  const float* K = (const float*)d_in[1];
  const float* V = (const float*)d_in[2];
  float* O = (float*)d_out;

  if (ws_size >= NEED_B) {
    float*    wsf  = (float*)d_ws;
    uint32_t* mask = (uint32_t*)d_ws;
    __bf16*   Kb   = (__bf16*)(wsf + WS_KB_F);
    __bf16*   Vt   = (__bf16*)(wsf + WS_VT_F);
    prep_all<<<dim3(4096 + 8192 + 16384), dim3(256), 0, stream>>>(K, V, Kb, Vt, mask);
    if (ws_size >= NEED_A) {
      float* U  = wsf + WS_U_F;
      float* LP = wsf + WS_LP_F;
      attn_bf16<<<dim3(2048), dim3(256), 0, stream>>>(Q, Kb, Vt, mask, O, U, LP, 1);
      attn_combine<<<dim3(8192), dim3(256), 0, stream>>>(U, LP, O);
    } else {
      attn_bf16<<<dim3(1024), dim3(256), 0, stream>>>(Q, Kb, Vt, mask, O, nullptr, nullptr, 0);
    }
  } else {
    attn_fwd_legacy<<<dim3(1024), dim3(256), 0, stream>>>(Q, K, V, O);
  }
}